// Round 10
// baseline (3017.056 us; speedup 1.0000x reference)
//
#include <hip/hip_runtime.h>
#include <hip/hip_bf16.h>
#include <cstddef>
#include <cstdint>

#define BB 64
#define TT 1024
#define HH 512
#define II 64
#define OO 8
#define NOISE_STD 0.05f
#define ALPHA 0.2f

#define NCL 8            // cliques (each on one XCD in local mode)
#define SLICES 16        // blocks (column slices) per clique
#define BT 4             // batches per GROUP (2 groups per clique -> 8 batches)
#define K4EXT 160
#define R2STRIDE 328     // r2 row stride in half2 slots

#define EXGRP (2 * BT * HH)   // words per group region (2 parities)
#define EXCQ  (2 * EXGRP)     // words per clique (2 groups)

typedef _Float16 half2_t __attribute__((ext_vector_type(2)));
typedef unsigned int uint32;
typedef uint32 uint4_t __attribute__((ext_vector_type(4)));

#if __has_builtin(__builtin_amdgcn_fdot2)
__device__ __forceinline__ float fdot2f(half2_t a, half2_t b, float c) {
    return __builtin_amdgcn_fdot2(a, b, c, false);
}
#else
__device__ __forceinline__ float fdot2f(half2_t a, half2_t b, float c) {
    return c + (float)a[0] * (float)b[0] + (float)a[1] * (float)b[1];
}
#endif

__device__ __forceinline__ half2_t pkrtz(float a, float b) {
    return __builtin_bit_cast(half2_t, __builtin_amdgcn_cvt_pkrtz(a, b));
}

// 16B coherent load at L3 scope — cross-XCD safe
__device__ __forceinline__ uint4_t load4_sc1(const uint32* p) {
    uint4_t v;
    asm volatile("global_load_dwordx4 %0, %1, off sc1\n\t"
                 "s_waitcnt vmcnt(0)"
                 : "=v"(v) : "v"(p) : "memory");
    return v;
}
// 16B load at L2 scope (bypasses L1, reads the XCD-shared L2) — intra-XCD
__device__ __forceinline__ uint4_t load4_sc0(const uint32* p) {
    uint4_t v;
    asm volatile("global_load_dwordx4 %0, %1, off sc0\n\t"
                 "s_waitcnt vmcnt(0)"
                 : "=v"(v) : "v"(p) : "memory");
    return v;
}
// plain store: lands in the XCD-shared (write-back) L2 — intra-XCD publish
__device__ __forceinline__ void store1_plain(uint32* p, uint32 v) {
    asm volatile("global_store_dword %0, %1, off" :: "v"(p), "v"(v) : "memory");
}

__global__ __launch_bounds__(512, 2)
void rnn_clique(const float* __restrict__ input, const float* __restrict__ noise,
                const float* __restrict__ wi, const float* __restrict__ si,
                const float* __restrict__ wrec, const float* __restrict__ bvec,
                const float* __restrict__ wo, const float* __restrict__ so,
                const float* __restrict__ wi_mask, const float* __restrict__ wrec_mask,
                const float* __restrict__ wo_mask, const float* __restrict__ h0,
                uint32* __restrict__ ex, float* __restrict__ out,
                float* __restrict__ traj)
{
    const int tid  = threadIdx.x;
    // clique = bid mod 8 -> all 16 blocks of a clique share an XCD under
    // round-robin dispatch (verified at runtime; sc1 fallback otherwise)
    const int cq   = blockIdx.x & 7;
    const int sl   = blockIdx.x >> 3;
    const int wv   = tid >> 6;
    const int lane = tid & 63;

    __shared__ half2_t w2[K4EXT * 64];            // eff-weight slice staging, 40 KB
    __shared__ half2_t r2[2][2][BT][R2STRIDE];    // [grp][par][b][slot], 41 KB
    __shared__ float   part[BT][8][32];           // matvec partials (shared A/B)
    __shared__ half2_t wo2[256];                  // wo_eff column (sl<8)
    __shared__ int     mode_sh;

    uint32* aux = ex + (size_t)NCL * EXCQ;        // handshake region

    if (tid == 0) {
        uint32 xcc;
        asm volatile("s_getreg_b32 %0, hwreg(HW_REG_XCC_ID)" : "=s"(xcc));
        xcc &= 0xFFu;
        __hip_atomic_store(aux + cq * SLICES + sl, (1u << 16) | xcc,
                           __ATOMIC_RELAXED, __HIP_MEMORY_SCOPE_AGENT);
    }

    // ---------------- stage extended weight slice ----------------
    {
        const int c = tid & 31, kg = tid >> 5;
        const int gc = sl * 32 + c;
        for (int m = 0; m < 10; ++m) {
            int k4 = m * 16 + kg;
            float v[4];
            #pragma unroll
            for (int q = 0; q < 4; ++q) {
                int kap = k4 * 4 + q;
                float x;
                if (kap < HH) {
                    x = fabsf(wrec[(size_t)kap * HH + gc]) * wrec_mask[(size_t)kap * HH + gc];
                } else if (kap < HH + II) {
                    int i = kap - HH;
                    x = wi[(size_t)i * HH + gc] * si[i] * wi_mask[(size_t)i * HH + gc];
                } else if (kap == HH + II) {
                    x = bvec[gc];
                } else {
                    x = 0.f;
                }
                v[q] = x;
            }
            w2[k4 * 64 + c * 2]     = pkrtz(v[0], v[1]);
            w2[k4 * 64 + c * 2 + 1] = pkrtz(v[2], v[3]);
        }
    }
    if (sl < OO && tid < 256) {
        int k2 = tid, o = sl;
        float v0 = wo[(size_t)(2 * k2) * OO + o] * so[o] * wo_mask[(size_t)(2 * k2) * OO + o];
        float v1 = wo[(size_t)(2 * k2 + 1) * OO + o] * so[o] * wo_mask[(size_t)(2 * k2 + 1) * OO + o];
        wo2[k2] = pkrtz(v0, v1);
    }
    if (tid < 128) {                 // h slots of parity-0 buffers from relu(h0)
        int k4 = tid;
        float v0 = fmaxf(h0[4 * k4 + 0], 0.f), v1 = fmaxf(h0[4 * k4 + 1], 0.f);
        float v2 = fmaxf(h0[4 * k4 + 2], 0.f), v3 = fmaxf(h0[4 * k4 + 3], 0.f);
        half2_t p0 = pkrtz(v0, v1), p1 = pkrtz(v2, v3);
        for (int g = 0; g < 2; ++g)
            for (int b = 0; b < BT; ++b) {
                r2[g][0][b][2 * k4] = p0; r2[g][0][b][2 * k4 + 1] = p1;
            }
    }
    if (tid < 16) {                  // bias + pads, all grp/par/b
        int g = tid & 1, par = (tid >> 1) & 1, b = tid >> 2;
        r2[g][par][b][288] = half2_t{(_Float16)1.f, (_Float16)0.f};
        for (int s = 289; s < R2STRIDE; ++s) r2[g][par][b][s] = half2_t{(_Float16)0.f, (_Float16)0.f};
    }
    if (wv >= 4 && lane < 32) {      // x(0) for both groups
        int b = wv - 4, i2 = lane;
        const float* xpA = input + ((size_t)(cq * 8 + b) * TT + 0) * II + 2 * i2;
        const float* xpB = input + ((size_t)(cq * 8 + 4 + b) * TT + 0) * II + 2 * i2;
        r2[0][0][b][256 + i2] = pkrtz(xpA[0], xpA[1]);
        r2[1][0][b][256 + i2] = pkrtz(xpB[0], xpB[1]);
    }

    // persistent per-lane state for finalize lanes (both groups)
    float hA = 0.f, hB = 0.f, nA0 = 0.f, nA1 = 0.f, nB0 = 0.f, nB1 = 0.f;
    float *trajpA = nullptr, *trajpB = nullptr;
    const float *noisepA = nullptr, *noisepB = nullptr;
    uint32 *exwA = nullptr, *exwB = nullptr;
    if (wv < BT && lane < 32) {
        int b = wv, c = lane, gc = sl * 32 + c;
        int bgA = cq * 8 + b, bgB = cq * 8 + 4 + b;
        hA = h0[gc]; hB = hA;
        noisepA = noise + (size_t)bgA * TT * HH;
        noisepB = noise + (size_t)bgB * TT * HH;
        trajpA  = traj + (size_t)bgA * (TT + 1) * HH;
        trajpB  = traj + (size_t)bgB * (TT + 1) * HH;
        nA0 = noisepA[gc];              nB0 = noisepB[gc];
        nA1 = noisepA[(size_t)HH + gc]; nB1 = noisepB[(size_t)HH + gc];
        trajpA[gc] = hA; trajpB[gc] = hB;
        exwA = ex + (size_t)cq * EXCQ + (size_t)b * HH + gc;
        exwB = exwA + EXGRP;
    }
    __syncthreads();

    const int c_    = lane & 31;
    const int shalf = lane >> 5;
    const int seg   = wv * 2 + shalf;          // 0..15

    // hoist weights to registers (shared by both groups)
    half2_t wr[5][4];
    #pragma unroll
    for (int ch = 0; ch < 5; ++ch) {
        int k4b = seg * 10 + ch * 2;
        wr[ch][0] = w2[k4b * 64 + c_ * 2];
        wr[ch][1] = w2[k4b * 64 + c_ * 2 + 1];
        wr[ch][2] = w2[(k4b + 1) * 64 + c_ * 2];
        wr[ch][3] = w2[(k4b + 1) * 64 + c_ * 2 + 1];
    }

    // ---- collect the clique's XCD ids; uniform -> L2-local fast path ----
    if (wv == 0) {
        uint32 v = (1u << 16);
        for (;;) {
            if (lane < SLICES)
                v = __hip_atomic_load(aux + cq * SLICES + lane,
                                      __ATOMIC_RELAXED, __HIP_MEMORY_SCOPE_AGENT);
            if (__ballot((v >> 16) == 1u) == ~0ull) break;
            __builtin_amdgcn_s_sleep(1);
        }
        uint32 myx = v & 0xFFFFu;
        uint32 x0  = __shfl(myx, 0);
        bool eq = (lane < SLICES) ? (myx == x0) : true;
        if (lane == 0) mode_sh = (__ballot(eq) == ~0ull) ? 1 : 0;
    }
    __syncthreads();
    const bool local_mode = (mode_sh != 0);

    // gather mapping: thread covers 4 consecutive columns of one batch
    const int gb  = tid >> 7;
    const int k4g = tid & 127;
    uint32* exgA = ex + (size_t)cq * EXCQ + (size_t)gb * HH + (size_t)(4 * k4g);
    uint32* exgB = exgA + EXGRP;

#define MATVEC(G, P)                                                              \
    {                                                                             \
        float a0 = 0.f, a1 = 0.f, a2 = 0.f, a3 = 0.f;                             \
        _Pragma("unroll")                                                         \
        for (int ch = 0; ch < 5; ++ch) {                                          \
            int k2b = seg * 20 + ch * 4;                                          \
            {                                                                     \
                half2_t ra = r2[G][P][0][k2b],     rb = r2[G][P][0][k2b + 1];     \
                half2_t rc = r2[G][P][0][k2b + 2], rd = r2[G][P][0][k2b + 3];     \
                a0 = fdot2f(ra, wr[ch][0], a0); a0 = fdot2f(rb, wr[ch][1], a0);   \
                a0 = fdot2f(rc, wr[ch][2], a0); a0 = fdot2f(rd, wr[ch][3], a0);   \
            }                                                                     \
            {                                                                     \
                half2_t ra = r2[G][P][1][k2b],     rb = r2[G][P][1][k2b + 1];     \
                half2_t rc = r2[G][P][1][k2b + 2], rd = r2[G][P][1][k2b + 3];     \
                a1 = fdot2f(ra, wr[ch][0], a1); a1 = fdot2f(rb, wr[ch][1], a1);   \
                a1 = fdot2f(rc, wr[ch][2], a1); a1 = fdot2f(rd, wr[ch][3], a1);   \
            }                                                                     \
            {                                                                     \
                half2_t ra = r2[G][P][2][k2b],     rb = r2[G][P][2][k2b + 1];     \
                half2_t rc = r2[G][P][2][k2b + 2], rd = r2[G][P][2][k2b + 3];     \
                a2 = fdot2f(ra, wr[ch][0], a2); a2 = fdot2f(rb, wr[ch][1], a2);   \
                a2 = fdot2f(rc, wr[ch][2], a2); a2 = fdot2f(rd, wr[ch][3], a2);   \
            }                                                                     \
            {                                                                     \
                half2_t ra = r2[G][P][3][k2b],     rb = r2[G][P][3][k2b + 1];     \
                half2_t rc = r2[G][P][3][k2b + 2], rd = r2[G][P][3][k2b + 3];     \
                a3 = fdot2f(ra, wr[ch][0], a3); a3 = fdot2f(rb, wr[ch][1], a3);   \
                a3 = fdot2f(rc, wr[ch][2], a3); a3 = fdot2f(rd, wr[ch][3], a3);   \
            }                                                                     \
        }                                                                         \
        a0 += __shfl_xor(a0, 32); a1 += __shfl_xor(a1, 32);                       \
        a2 += __shfl_xor(a2, 32); a3 += __shfl_xor(a3, 32);                       \
        if (shalf == 0) {                                                         \
            part[0][wv][c_] = a0; part[1][wv][c_] = a1;                           \
            part[2][wv][c_] = a2; part[3][wv][c_] = a3;                           \
        }                                                                         \
    }

#define GATHER(EXG, PAR, TAG, G, P2)                                              \
    {                                                                             \
        const uint32* g0 = (EXG) + (size_t)(PAR) * (BT * HH);                     \
        uint4_t w; int spins = 0;                                                 \
        if (local_mode) {                                                         \
            for (;;) {                                                            \
                w = load4_sc0(g0);                                                \
                if ((w[0] >> 16) == (TAG) && (w[1] >> 16) == (TAG) &&             \
                    (w[2] >> 16) == (TAG) && (w[3] >> 16) == (TAG)) break;        \
                if (++spins > 16) __builtin_amdgcn_s_sleep(1);                    \
            }                                                                     \
        } else {                                                                  \
            for (;;) {                                                            \
                w = load4_sc1(g0);                                                \
                if ((w[0] >> 16) == (TAG) && (w[1] >> 16) == (TAG) &&             \
                    (w[2] >> 16) == (TAG) && (w[3] >> 16) == (TAG)) break;        \
                __builtin_amdgcn_s_sleep(1);                                      \
            }                                                                     \
        }                                                                         \
        uint32 q0 = (w[0] & 0xFFFFu) | (w[1] << 16);                              \
        uint32 q1 = (w[2] & 0xFFFFu) | (w[3] << 16);                              \
        r2[G][P2][gb][2 * k4g]     = __builtin_bit_cast(half2_t, q0);             \
        r2[G][P2][gb][2 * k4g + 1] = __builtin_bit_cast(half2_t, q1);             \
    }

    for (int t = 0; t < TT; ++t) {
        const int p = t & 1;
        const uint32 tagN = (uint32)(t + 2);   // tag of h(t+1); memset-0 / stale never match

        // ---------- phase 1: matvec A(t) ----------
        MATVEC(0, p);
        __syncthreads();   // B1

        // ---------- phase 3: finalize+publish A(t+1) | gather B(t) | aux ----------
        if (wv < BT && lane < 32) {
            int b = wv, c = lane, gc = sl * 32 + c;
            float mv = 0.f;
            #pragma unroll
            for (int m = 0; m < 8; ++m) mv += part[b][m][c];
            float hn = (1.f - ALPHA) * hA + ALPHA * mv + NOISE_STD * nA0;
            hA = hn;
            uint32 r16 = __builtin_bit_cast(uint32,
                           __builtin_amdgcn_cvt_pkrtz(fmaxf(hn, 0.f), 0.f)) & 0xFFFFu;
            uint32 word = (tagN << 16) | r16;
            if (local_mode) store1_plain(exwA + (size_t)(p ^ 1) * (BT * HH), word);
            else __hip_atomic_store(exwA + (size_t)(p ^ 1) * (BT * HH), word,
                                    __ATOMIC_RELAXED, __HIP_MEMORY_SCOPE_AGENT);
            trajpA[(size_t)(t + 1) * HH + gc] = hn;
            nA0 = nA1;
        }
        if (t > 0) GATHER(exgB, p, (uint32)(t + 1), 1, p);   // h_B(t) -> r2B[p]
        // deferred vmem work (keeps the poll's vmcnt clean)
        if (wv < BT && lane < 32) {
            int gc = sl * 32 + lane;
            int tn = (t + 2 < TT) ? (t + 2) : (TT - 1);
            nA1 = noisepA[(size_t)tn * HH + gc];
        } else if (wv >= 4) {
            if (sl < OO && t > 0) {      // out_A(t-1) from r2A[p]
                int b = wv - 4, k2 = lane * 4;
                float q = 0.f;
                q = fdot2f(r2[0][p][b][k2],     wo2[k2],     q);
                q = fdot2f(r2[0][p][b][k2 + 1], wo2[k2 + 1], q);
                q = fdot2f(r2[0][p][b][k2 + 2], wo2[k2 + 2], q);
                q = fdot2f(r2[0][p][b][k2 + 3], wo2[k2 + 3], q);
                #pragma unroll
                for (int d = 32; d >= 1; d >>= 1) q += __shfl_xor(q, d);
                if (lane == 0) out[((size_t)(cq * 8 + b) * TT + (t - 1)) * OO + sl] = q;
            }
            if (lane < 32) {             // x_A(t+1) -> r2A[p^1]
                int b = wv - 4, i2 = lane;
                int tn = (t + 1 < TT) ? (t + 1) : (TT - 1);
                const float* xp = input + ((size_t)(cq * 8 + b) * TT + tn) * II + 2 * i2;
                r2[0][p ^ 1][b][256 + i2] = pkrtz(xp[0], xp[1]);
            }
        }
        __syncthreads();   // B2

        // ---------- phase 5: matvec B(t) ----------
        MATVEC(1, p);
        __syncthreads();   // B3

        // ---------- phase 7: finalize+publish B(t+1) | gather A(t+1) | aux ----------
        if (wv < BT && lane < 32) {
            int b = wv, c = lane, gc = sl * 32 + c;
            float mv = 0.f;
            #pragma unroll
            for (int m = 0; m < 8; ++m) mv += part[b][m][c];
            float hn = (1.f - ALPHA) * hB + ALPHA * mv + NOISE_STD * nB0;
            hB = hn;
            uint32 r16 = __builtin_bit_cast(uint32,
                           __builtin_amdgcn_cvt_pkrtz(fmaxf(hn, 0.f), 0.f)) & 0xFFFFu;
            uint32 word = (tagN << 16) | r16;
            if (local_mode) store1_plain(exwB + (size_t)(p ^ 1) * (BT * HH), word);
            else __hip_atomic_store(exwB + (size_t)(p ^ 1) * (BT * HH), word,
                                    __ATOMIC_RELAXED, __HIP_MEMORY_SCOPE_AGENT);
            trajpB[(size_t)(t + 1) * HH + gc] = hn;
            nB0 = nB1;
        }
        GATHER(exgA, p ^ 1, tagN, 0, p ^ 1);                 // h_A(t+1) -> r2A[p^1]
        if (wv < BT && lane < 32) {
            int gc = sl * 32 + lane;
            int tn = (t + 2 < TT) ? (t + 2) : (TT - 1);
            nB1 = noisepB[(size_t)tn * HH + gc];
        } else if (wv >= 4) {
            if (sl < OO && t > 0) {      // out_B(t-1) from r2B[p]
                int b = wv - 4, k2 = lane * 4;
                float q = 0.f;
                q = fdot2f(r2[1][p][b][k2],     wo2[k2],     q);
                q = fdot2f(r2[1][p][b][k2 + 1], wo2[k2 + 1], q);
                q = fdot2f(r2[1][p][b][k2 + 2], wo2[k2 + 2], q);
                q = fdot2f(r2[1][p][b][k2 + 3], wo2[k2 + 3], q);
                #pragma unroll
                for (int d = 32; d >= 1; d >>= 1) q += __shfl_xor(q, d);
                if (lane == 0) out[((size_t)(cq * 8 + 4 + b) * TT + (t - 1)) * OO + sl] = q;
            }
            if (lane < 32) {             // x_B(t+1) -> r2B[p^1]
                int b = wv - 4, i2 = lane;
                int tn = (t + 1 < TT) ? (t + 1) : (TT - 1);
                const float* xp = input + ((size_t)(cq * 8 + 4 + b) * TT + tn) * II + 2 * i2;
                r2[1][p ^ 1][b][256 + i2] = pkrtz(xp[0], xp[1]);
            }
        }
        __syncthreads();   // B4
    }

    // ---------- epilogue ----------
    GATHER(exgB, 0, (uint32)(TT + 1), 1, 0);   // h_B(TT) -> r2B[0]
    __syncthreads();
    if (wv >= 4 && sl < OO) {
        int b = wv - 4, k2 = lane * 4;
        float qa = 0.f, qb = 0.f;
        qa = fdot2f(r2[0][0][b][k2],     wo2[k2],     qa);
        qa = fdot2f(r2[0][0][b][k2 + 1], wo2[k2 + 1], qa);
        qa = fdot2f(r2[0][0][b][k2 + 2], wo2[k2 + 2], qa);
        qa = fdot2f(r2[0][0][b][k2 + 3], wo2[k2 + 3], qa);
        qb = fdot2f(r2[1][0][b][k2],     wo2[k2],     qb);
        qb = fdot2f(r2[1][0][b][k2 + 1], wo2[k2 + 1], qb);
        qb = fdot2f(r2[1][0][b][k2 + 2], wo2[k2 + 2], qb);
        qb = fdot2f(r2[1][0][b][k2 + 3], wo2[k2 + 3], qb);
        #pragma unroll
        for (int d = 32; d >= 1; d >>= 1) { qa += __shfl_xor(qa, d); qb += __shfl_xor(qb, d); }
        if (lane == 0) {
            out[((size_t)(cq * 8 + b) * TT + (TT - 1)) * OO + sl] = qa;
            out[((size_t)(cq * 8 + 4 + b) * TT + (TT - 1)) * OO + sl] = qb;
        }
    }
}

// ---------------- host launcher ----------------
extern "C" void kernel_launch(void* const* d_in, const int* in_sizes, int n_in,
                              void* d_out, int out_size, void* d_ws, size_t ws_size,
                              hipStream_t stream) {
    const float* input     = (const float*)d_in[0];
    const float* noise     = (const float*)d_in[1];
    const float* wi        = (const float*)d_in[2];
    const float* si        = (const float*)d_in[3];
    const float* wrec      = (const float*)d_in[4];
    const float* bvec      = (const float*)d_in[5];
    const float* wo        = (const float*)d_in[6];
    const float* so        = (const float*)d_in[7];
    const float* wi_mask   = (const float*)d_in[8];
    const float* wrec_mask = (const float*)d_in[9];
    const float* wo_mask   = (const float*)d_in[10];
    const float* h0        = (const float*)d_in[11];

    float* out  = (float*)d_out;
    float* traj = out + (size_t)BB * TT * OO;
    uint32* ex  = (uint32*)d_ws;

    // clear exchange + handshake tags every call (stale-tag safety; replay-safe)
    (void)hipMemsetAsync(d_ws, 0,
        (size_t)(NCL * EXCQ + NCL * SLICES) * sizeof(uint32), stream);

    rnn_clique<<<dim3(NCL * SLICES), dim3(512), 0, stream>>>(
        input, noise, wi, si, wrec, bvec, wo, so,
        wi_mask, wrec_mask, wo_mask, h0, ex, out, traj);
}

// Round 12
// 2171.962 us; speedup vs baseline: 1.3891x; 1.3891x over previous
//
#include <hip/hip_runtime.h>
#include <hip/hip_bf16.h>
#include <cstddef>
#include <cstdint>

#define BB 64
#define TT 1024
#define HH 512
#define II 64
#define OO 8
#define NOISE_STD 0.05f
#define ALPHA 0.2f

#define NCL 16           // cliques
#define SLICES 16        // blocks (column slices) per clique
#define BT 4             // batches per clique
#define K4EXT 160
#define R2STRIDE 328     // r2 row stride in half2 slots

#define EXCQ (2 * BT * HH)    // exchange words per clique (2 parities)

typedef _Float16 half2_t __attribute__((ext_vector_type(2)));
typedef unsigned int uint32;
typedef uint32 uint4_t __attribute__((ext_vector_type(4)));

#if __has_builtin(__builtin_amdgcn_fdot2)
__device__ __forceinline__ float fdot2f(half2_t a, half2_t b, float c) {
    return __builtin_amdgcn_fdot2(a, b, c, false);
}
#else
__device__ __forceinline__ float fdot2f(half2_t a, half2_t b, float c) {
    return c + (float)a[0] * (float)b[0] + (float)a[1] * (float)b[1];
}
#endif

__device__ __forceinline__ half2_t pkrtz(float a, float b) {
    return __builtin_bit_cast(half2_t, __builtin_amdgcn_cvt_pkrtz(a, b));
}

// 16B coherent load at L3 scope — cross-XCD safe
__device__ __forceinline__ uint4_t load4_sc1(const uint32* p) {
    uint4_t v;
    asm volatile("global_load_dwordx4 %0, %1, off sc1\n\t"
                 "s_waitcnt vmcnt(0)"
                 : "=v"(v) : "v"(p) : "memory");
    return v;
}
// 16B load at L2 scope (bypasses L1, reads the XCD-shared L2) — intra-XCD
__device__ __forceinline__ uint4_t load4_sc0(const uint32* p) {
    uint4_t v;
    asm volatile("global_load_dwordx4 %0, %1, off sc0\n\t"
                 "s_waitcnt vmcnt(0)"
                 : "=v"(v) : "v"(p) : "memory");
    return v;
}
// plain store: lands in the XCD-shared (write-back) L2 — intra-XCD publish
__device__ __forceinline__ void store1_plain(uint32* p, uint32 v) {
    asm volatile("global_store_dword %0, %1, off" :: "v"(p), "v"(v) : "memory");
}

__global__ __launch_bounds__(512, 2)
void rnn_clique(const float* __restrict__ input, const float* __restrict__ noise,
                const float* __restrict__ wi, const float* __restrict__ si,
                const float* __restrict__ wrec, const float* __restrict__ bvec,
                const float* __restrict__ wo, const float* __restrict__ so,
                const float* __restrict__ wi_mask, const float* __restrict__ wrec_mask,
                const float* __restrict__ wo_mask, const float* __restrict__ h0,
                uint32* __restrict__ ex, float* __restrict__ out,
                float* __restrict__ traj)
{
    const int tid  = threadIdx.x;
    // clique = bid mod 16 -> all 16 blocks of a clique share bid mod 8
    // -> same XCD under round-robin dispatch (verified at runtime; sc1 fallback)
    const int cq   = blockIdx.x & 15;
    const int sl   = blockIdx.x >> 4;
    const int wv   = tid >> 6;
    const int lane = tid & 63;

    __shared__ half2_t w2[K4EXT * 64];          // eff-weight slice staging, 40 KB
    __shared__ half2_t r2[2][BT][R2STRIDE];     // parity-double-buffered activations
    __shared__ float   part[BT][8][32];         // per-wave matvec partials
    __shared__ half2_t wo2[256];                // wo_eff column (sl<8)
    __shared__ int     mode_sh;

    uint32* aux = ex + (size_t)NCL * EXCQ;      // handshake region

    if (tid == 0) {
        uint32 xcc;
        asm volatile("s_getreg_b32 %0, hwreg(HW_REG_XCC_ID)" : "=s"(xcc));
        xcc &= 0xFFu;
        __hip_atomic_store(aux + cq * SLICES + sl, (1u << 16) | xcc,
                           __ATOMIC_RELAXED, __HIP_MEMORY_SCOPE_AGENT);
    }

    // ---------------- stage extended weight slice ----------------
    {
        const int c = tid & 31, kg = tid >> 5;
        const int gc = sl * 32 + c;
        for (int m = 0; m < 10; ++m) {
            int k4 = m * 16 + kg;
            float v[4];
            #pragma unroll
            for (int q = 0; q < 4; ++q) {
                int kap = k4 * 4 + q;
                float x;
                if (kap < HH) {
                    x = fabsf(wrec[(size_t)kap * HH + gc]) * wrec_mask[(size_t)kap * HH + gc];
                } else if (kap < HH + II) {
                    int i = kap - HH;
                    x = wi[(size_t)i * HH + gc] * si[i] * wi_mask[(size_t)i * HH + gc];
                } else if (kap == HH + II) {
                    x = bvec[gc];
                } else {
                    x = 0.f;
                }
                v[q] = x;
            }
            w2[k4 * 64 + c * 2]     = pkrtz(v[0], v[1]);
            w2[k4 * 64 + c * 2 + 1] = pkrtz(v[2], v[3]);
        }
    }
    if (sl < OO && tid < 256) {
        int k2 = tid, o = sl;
        float v0 = wo[(size_t)(2 * k2) * OO + o] * so[o] * wo_mask[(size_t)(2 * k2) * OO + o];
        float v1 = wo[(size_t)(2 * k2 + 1) * OO + o] * so[o] * wo_mask[(size_t)(2 * k2 + 1) * OO + o];
        wo2[k2] = pkrtz(v0, v1);
    }
    if (tid < 128) {                 // r2[0] h-slots from relu(h0)
        int k4 = tid;
        float v0 = fmaxf(h0[4 * k4 + 0], 0.f), v1 = fmaxf(h0[4 * k4 + 1], 0.f);
        float v2 = fmaxf(h0[4 * k4 + 2], 0.f), v3 = fmaxf(h0[4 * k4 + 3], 0.f);
        half2_t p0 = pkrtz(v0, v1), p1 = pkrtz(v2, v3);
        for (int b = 0; b < BT; ++b) { r2[0][b][2 * k4] = p0; r2[0][b][2 * k4 + 1] = p1; }
    }
    if (tid < 2 * BT) {              // bias + pads in BOTH parity buffers
        int par = tid & 1, b = tid >> 1;
        r2[par][b][288] = half2_t{(_Float16)1.f, (_Float16)0.f};
        for (int s = 289; s < R2STRIDE; ++s) r2[par][b][s] = half2_t{(_Float16)0.f, (_Float16)0.f};
    }
    if (wv >= 4 && lane < 32) {      // x(0) into r2[0]
        int b = wv - 4, i2 = lane;
        const float* xp = input + ((size_t)(cq * BT + b) * TT + 0) * II + 2 * i2;
        r2[0][b][256 + i2] = pkrtz(xp[0], xp[1]);
    }

    // persistent per-lane state for finalize lanes (waves 0..3, lanes<32)
    float h_st = 0.f, n_reg = 0.f, n_nxt = 0.f;
    int   gcf = 0;
    float* trajp = nullptr;
    const float* noisep = nullptr;
    uint32* exw = nullptr;
    if (wv < BT && lane < 32) {
        int b = wv, c = lane;
        gcf    = sl * 32 + c;
        int bg = cq * BT + b;
        h_st   = h0[gcf];
        noisep = noise + (size_t)bg * TT * HH;
        trajp  = traj + (size_t)bg * (TT + 1) * HH;
        n_reg  = noisep[gcf];                 // noise[b][0]
        n_nxt  = noisep[(size_t)HH + gcf];    // noise[b][1]
        trajp[gcf] = h_st;
        exw = ex + (size_t)(cq * 2 * BT + b) * HH + gcf;   // parity-0 base
    }
    __syncthreads();

    const int c_    = lane & 31;
    const int shalf = lane >> 5;
    const int seg   = wv * 2 + shalf;          // 0..15

    // hoist this thread's weights into registers (20 half2)
    half2_t wr[5][4];
    #pragma unroll
    for (int ch = 0; ch < 5; ++ch) {
        int k4b = seg * 10 + ch * 2;
        wr[ch][0] = w2[k4b * 64 + c_ * 2];
        wr[ch][1] = w2[k4b * 64 + c_ * 2 + 1];
        wr[ch][2] = w2[(k4b + 1) * 64 + c_ * 2];
        wr[ch][3] = w2[(k4b + 1) * 64 + c_ * 2 + 1];
    }

    // ---- collect the clique's XCD ids; uniform -> L2-local fast path ----
    if (wv == 0) {
        uint32 v = (1u << 16);
        for (;;) {
            if (lane < SLICES)
                v = __hip_atomic_load(aux + cq * SLICES + lane,
                                      __ATOMIC_RELAXED, __HIP_MEMORY_SCOPE_AGENT);
            if (__ballot((v >> 16) == 1u) == ~0ull) break;
            __builtin_amdgcn_s_sleep(1);
        }
        uint32 myx = v & 0xFFFFu;
        uint32 x0  = __shfl(myx, 0);
        bool eq = (lane < SLICES) ? (myx == x0) : true;
        if (lane == 0) mode_sh = (__ballot(eq) == ~0ull) ? 1 : 0;
    }
    __syncthreads();
    const bool local_mode = (mode_sh != 0);

    // gather mapping: thread covers 4 consecutive columns (one dwordx4)
    const int gb  = tid >> 7;          // batch 0..3
    const int k4g = tid & 127;         // column group
    uint32* exg0 = ex + (size_t)(cq * 2 * BT + gb) * HH + (size_t)(4 * k4g);
    const size_t expar = (size_t)BT * HH;

    for (int t = 0; t < TT; ++t) {
        const int p = t & 1;

        // ---- early vmem issue: latency hides under matvec+B1+finalize ----
        float n_fly = 0.f, xa = 0.f, xb = 0.f;
        if (wv < BT && lane < 32) {
            int tn = (t + 2 < TT) ? (t + 2) : (TT - 1);
            n_fly = noisep[(size_t)tn * HH + gcf];          // noise(t+2)
        } else if (wv >= 4 && lane < 32) {
            int b = wv - 4;
            int tn = (t + 1 < TT) ? (t + 1) : (TT - 1);
            const float* xp = input + ((size_t)(cq * BT + b) * TT + tn) * II + 2 * lane;
            xa = xp[0]; xb = xp[1];                         // x(t+1)
        }

        // ---- matvec from r2[p] with register weights ----
        float acc0 = 0.f, acc1 = 0.f, acc2 = 0.f, acc3 = 0.f;
        #pragma unroll
        for (int ch = 0; ch < 5; ++ch) {
            int k2b = seg * 20 + ch * 4;
            {
                half2_t ra = r2[p][0][k2b],     rb = r2[p][0][k2b + 1];
                half2_t rc = r2[p][0][k2b + 2], rd = r2[p][0][k2b + 3];
                acc0 = fdot2f(ra, wr[ch][0], acc0); acc0 = fdot2f(rb, wr[ch][1], acc0);
                acc0 = fdot2f(rc, wr[ch][2], acc0); acc0 = fdot2f(rd, wr[ch][3], acc0);
            }
            {
                half2_t ra = r2[p][1][k2b],     rb = r2[p][1][k2b + 1];
                half2_t rc = r2[p][1][k2b + 2], rd = r2[p][1][k2b + 3];
                acc1 = fdot2f(ra, wr[ch][0], acc1); acc1 = fdot2f(rb, wr[ch][1], acc1);
                acc1 = fdot2f(rc, wr[ch][2], acc1); acc1 = fdot2f(rd, wr[ch][3], acc1);
            }
            {
                half2_t ra = r2[p][2][k2b],     rb = r2[p][2][k2b + 1];
                half2_t rc = r2[p][2][k2b + 2], rd = r2[p][2][k2b + 3];
                acc2 = fdot2f(ra, wr[ch][0], acc2); acc2 = fdot2f(rb, wr[ch][1], acc2);
                acc2 = fdot2f(rc, wr[ch][2], acc2); acc2 = fdot2f(rd, wr[ch][3], acc2);
            }
            {
                half2_t ra = r2[p][3][k2b],     rb = r2[p][3][k2b + 1];
                half2_t rc = r2[p][3][k2b + 2], rd = r2[p][3][k2b + 3];
                acc3 = fdot2f(ra, wr[ch][0], acc3); acc3 = fdot2f(rb, wr[ch][1], acc3);
                acc3 = fdot2f(rc, wr[ch][2], acc3); acc3 = fdot2f(rd, wr[ch][3], acc3);
            }
        }
        acc0 += __shfl_xor(acc0, 32);
        acc1 += __shfl_xor(acc1, 32);
        acc2 += __shfl_xor(acc2, 32);
        acc3 += __shfl_xor(acc3, 32);
        if (shalf == 0) {
            part[0][wv][c_] = acc0;
            part[1][wv][c_] = acc1;
            part[2][wv][c_] = acc2;
            part[3][wv][c_] = acc3;
        }
        __syncthreads();   // B1

        const uint32 tag = (uint32)(t + 2);      // tag of h(t+1); memset-0 never matches
        const size_t poff = (size_t)p * expar;   // h(t+1) parity

        // ---- finalize + publish only (everything else deferred past gather) ----
        if (wv < BT && lane < 32) {
            int b = wv;
            float mv = 0.f;
            #pragma unroll
            for (int m = 0; m < 8; ++m) mv += part[b][m][c_];
            float hn = (1.f - ALPHA) * h_st + ALPHA * mv + NOISE_STD * n_reg;
            h_st = hn;
            uint32 r16 = __builtin_bit_cast(uint32,
                           __builtin_amdgcn_cvt_pkrtz(fmaxf(hn, 0.f), 0.f)) & 0xFFFFu;
            uint32 word = (tag << 16) | r16;
            if (local_mode) {
                store1_plain(exw + poff, word);
            } else {
                __hip_atomic_store(exw + poff, word,
                                   __ATOMIC_RELAXED, __HIP_MEMORY_SCOPE_AGENT);
            }
        }

        // ---- gather h(t+1) -> r2[p^1] (all threads; minimal vmem in flight) ----
        {
            const uint32* g0 = exg0 + poff;
            uint4_t w;
            if (local_mode) {
                for (;;) {                      // hot spin: 1 block/CU
                    w = load4_sc0(g0);
                    if ((w[0] >> 16) == tag && (w[1] >> 16) == tag &&
                        (w[2] >> 16) == tag && (w[3] >> 16) == tag) break;
                }
            } else {
                for (;;) {
                    w = load4_sc1(g0);
                    if ((w[0] >> 16) == tag && (w[1] >> 16) == tag &&
                        (w[2] >> 16) == tag && (w[3] >> 16) == tag) break;
                    __builtin_amdgcn_s_sleep(1);
                }
            }
            uint32 q0 = (w[0] & 0xFFFFu) | (w[1] << 16);
            uint32 q1 = (w[2] & 0xFFFFu) | (w[3] << 16);
            r2[p ^ 1][gb][2 * k4g]     = __builtin_bit_cast(half2_t, q0);
            r2[p ^ 1][gb][2 * k4g + 1] = __builtin_bit_cast(half2_t, q1);
        }

        // ---- deferred work (off the rendezvous path, before B2) ----
        if (wv < BT && lane < 32) {
            trajp[(size_t)(t + 1) * HH + gcf] = h_st;   // output store
            n_reg = n_nxt;                              // noise pipeline shift
            n_nxt = n_fly;
        } else if (wv >= 4) {
            if (sl < OO && t > 0) {
                // out(t-1) = relu(h(t)) . wo  from r2[p] (untouched this step)
                int b = wv - 4;
                int k2 = lane * 4;
                float q = 0.f;
                q = fdot2f(r2[p][b][k2],     wo2[k2],     q);
                q = fdot2f(r2[p][b][k2 + 1], wo2[k2 + 1], q);
                q = fdot2f(r2[p][b][k2 + 2], wo2[k2 + 2], q);
                q = fdot2f(r2[p][b][k2 + 3], wo2[k2 + 3], q);
                #pragma unroll
                for (int d = 32; d >= 1; d >>= 1) q += __shfl_xor(q, d);
                if (lane == 0) out[((size_t)(cq * BT + b) * TT + (t - 1)) * OO + sl] = q;
            }
            if (lane < 32) {          // stage x(t+1) into r2[p^1] (from early load)
                int b = wv - 4;
                r2[p ^ 1][b][256 + lane] = pkrtz(xa, xb);
            }
        }
        __syncthreads();   // B2 (r2[p^1] complete; part[] consumed)
    }

    // ---- epilogue: out(TT-1) from r2[0] = relu(h(TT)) ----
    if (wv >= 4 && sl < OO) {
        int b = wv - 4;
        int k2 = lane * 4;
        float q = 0.f;
        q = fdot2f(r2[0][b][k2],     wo2[k2],     q);
        q = fdot2f(r2[0][b][k2 + 1], wo2[k2 + 1], q);
        q = fdot2f(r2[0][b][k2 + 2], wo2[k2 + 2], q);
        q = fdot2f(r2[0][b][k2 + 3], wo2[k2 + 3], q);
        #pragma unroll
        for (int d = 32; d >= 1; d >>= 1) q += __shfl_xor(q, d);
        if (lane == 0) out[((size_t)(cq * BT + b) * TT + (TT - 1)) * OO + sl] = q;
    }
}

// ---------------- host launcher ----------------
extern "C" void kernel_launch(void* const* d_in, const int* in_sizes, int n_in,
                              void* d_out, int out_size, void* d_ws, size_t ws_size,
                              hipStream_t stream) {
    const float* input     = (const float*)d_in[0];
    const float* noise     = (const float*)d_in[1];
    const float* wi        = (const float*)d_in[2];
    const float* si        = (const float*)d_in[3];
    const float* wrec      = (const float*)d_in[4];
    const float* bvec      = (const float*)d_in[5];
    const float* wo        = (const float*)d_in[6];
    const float* so        = (const float*)d_in[7];
    const float* wi_mask   = (const float*)d_in[8];
    const float* wrec_mask = (const float*)d_in[9];
    const float* wo_mask   = (const float*)d_in[10];
    const float* h0        = (const float*)d_in[11];

    float* out  = (float*)d_out;
    float* traj = out + (size_t)BB * TT * OO;
    uint32* ex  = (uint32*)d_ws;

    // clear exchange + handshake tags every call (stale-tag safety; replay-safe)
    (void)hipMemsetAsync(d_ws, 0,
        (size_t)(NCL * EXCQ + NCL * SLICES) * sizeof(uint32), stream);

    rnn_clique<<<dim3(NCL * SLICES), dim3(512), 0, stream>>>(
        input, noise, wi, si, wrec, bvec, wo, so,
        wi_mask, wrec_mask, wo_mask, h0, ex, out, traj);
}

// Round 13
// 1783.786 us; speedup vs baseline: 1.6914x; 1.2176x over previous
//
#include <hip/hip_runtime.h>
#include <hip/hip_bf16.h>
#include <cstddef>
#include <cstdint>

#define BB 64
#define TT 1024
#define HH 512
#define II 64
#define OO 8
#define NOISE_STD 0.05f
#define ALPHA 0.2f

#define NCLQ 64          // cliques = batches
#define SLC 4            // blocks per clique (128-column slices)
#define EXCQ (2 * HH)    // exchange words per clique (2 parities x 512)

typedef _Float16 half2_t __attribute__((ext_vector_type(2)));
typedef unsigned int uint32;
typedef uint32 uint4_t __attribute__((ext_vector_type(4)));

#if __has_builtin(__builtin_amdgcn_fdot2)
__device__ __forceinline__ float fdot2f(half2_t a, half2_t b, float c) {
    return __builtin_amdgcn_fdot2(a, b, c, false);
}
#else
__device__ __forceinline__ float fdot2f(half2_t a, half2_t b, float c) {
    return c + (float)a[0] * (float)b[0] + (float)a[1] * (float)b[1];
}
#endif

__device__ __forceinline__ half2_t pkrtz(float a, float b) {
    return __builtin_bit_cast(half2_t, __builtin_amdgcn_cvt_pkrtz(a, b));
}

// 16B coherent load at L3 scope — cross-XCD safe
__device__ __forceinline__ uint4_t load4_sc1(const uint32* p) {
    uint4_t v;
    asm volatile("global_load_dwordx4 %0, %1, off sc1\n\t"
                 "s_waitcnt vmcnt(0)"
                 : "=v"(v) : "v"(p) : "memory");
    return v;
}
// 16B load at L2 scope (bypasses L1, reads the XCD-shared L2) — intra-XCD
__device__ __forceinline__ uint4_t load4_sc0(const uint32* p) {
    uint4_t v;
    asm volatile("global_load_dwordx4 %0, %1, off sc0\n\t"
                 "s_waitcnt vmcnt(0)"
                 : "=v"(v) : "v"(p) : "memory");
    return v;
}
// plain store: lands in the XCD-shared (write-back) L2 — intra-XCD publish
__device__ __forceinline__ void store1_plain(uint32* p, uint32 v) {
    asm volatile("global_store_dword %0, %1, off" :: "v"(p), "v"(v) : "memory");
}

__global__ __launch_bounds__(512, 2)
void rnn_b1(const float* __restrict__ input, const float* __restrict__ noise,
            const float* __restrict__ wi, const float* __restrict__ si,
            const float* __restrict__ wrec, const float* __restrict__ bvec,
            const float* __restrict__ wo, const float* __restrict__ so,
            const float* __restrict__ wi_mask, const float* __restrict__ wrec_mask,
            const float* __restrict__ wo_mask, const float* __restrict__ h0,
            uint32* __restrict__ ex, float* __restrict__ out,
            float* __restrict__ traj)
{
    const int tid  = threadIdx.x;
    // clique = bid mod 64 -> the 4 blocks {cq, cq+64, cq+128, cq+192} share
    // bid mod 8 -> same XCD under round-robin dispatch (runtime-verified)
    const int cq   = blockIdx.x & 63;
    const int sl   = blockIdx.x >> 6;          // 0..3: column slice
    const int wv   = tid >> 6;
    const int lane = tid & 63;
    const int c    = tid & 127;                // column within slice
    const int ks   = tid >> 7;                 // k-segment 0..3
    const int gc   = sl * 128 + c;             // global column

    __shared__ half2_t r2[2][336];             // parity x slots (320 used)
    __shared__ float   part[4][128];           // k-segment partials
    __shared__ half2_t wo2[2][256];            // 2 wo_eff columns for this slice
    __shared__ int     mode_sh;

    uint32* aux = ex + (size_t)NCLQ * EXCQ;    // handshake region

    if (tid == 0) {
        uint32 xcc;
        asm volatile("s_getreg_b32 %0, hwreg(HW_REG_XCC_ID)" : "=s"(xcc));
        __hip_atomic_store(aux + cq * SLC + sl, (1u << 16) | (xcc & 0xFFu),
                           __ATOMIC_RELAXED, __HIP_MEMORY_SCOPE_AGENT);
    }

    // ---- stage this thread's 80 effective-weight pairs into REGISTERS ----
    // slot s = ks*80+j holds rows (2s, 2s+1) of the extended matrix, column gc.
    half2_t wr[80];
    #pragma unroll
    for (int j = 0; j < 80; ++j) {
        int k0 = (ks * 80 + j) * 2;
        int k1 = k0 + 1;
        float v0, v1;
        if (k0 < HH)           v0 = fabsf(wrec[(size_t)k0 * HH + gc]) * wrec_mask[(size_t)k0 * HH + gc];
        else if (k0 < HH + II) { int i = k0 - HH; v0 = wi[(size_t)i * HH + gc] * si[i] * wi_mask[(size_t)i * HH + gc]; }
        else if (k0 == HH + II)  v0 = bvec[gc];
        else                     v0 = 0.f;
        if (k1 < HH)           v1 = fabsf(wrec[(size_t)k1 * HH + gc]) * wrec_mask[(size_t)k1 * HH + gc];
        else if (k1 < HH + II) { int i = k1 - HH; v1 = wi[(size_t)i * HH + gc] * si[i] * wi_mask[(size_t)i * HH + gc]; }
        else if (k1 == HH + II)  v1 = bvec[gc];
        else                     v1 = 0.f;
        wr[j] = pkrtz(v0, v1);
    }

    // ---- one-time LDS init ----
    {   // wo_eff columns o = 2*sl, 2*sl+1
        int oo = tid >> 8, k2 = tid & 255, o = sl * 2 + oo;
        float v0 = wo[(size_t)(2 * k2) * OO + o]     * so[o] * wo_mask[(size_t)(2 * k2) * OO + o];
        float v1 = wo[(size_t)(2 * k2 + 1) * OO + o] * so[o] * wo_mask[(size_t)(2 * k2 + 1) * OO + o];
        wo2[oo][k2] = pkrtz(v0, v1);
    }
    if (tid < 256) {               // r2[0] h-slots from relu(h0)
        float v0 = fmaxf(h0[2 * tid], 0.f), v1 = fmaxf(h0[2 * tid + 1], 0.f);
        r2[0][tid] = pkrtz(v0, v1);
    }
    if (tid >= 256 && tid < 352) { // bias slot 288 + zero pads 289..335, BOTH parities
        int r = tid - 256;         // 0..95
        int par = r & 1, s = 288 + (r >> 1);
        r2[par][s] = (s == 288) ? half2_t{(_Float16)1.f, (_Float16)0.f}
                                : half2_t{(_Float16)0.f, (_Float16)0.f};
    }
    if (wv == 6 && lane < 32) {    // x(0) -> r2[0][256..287]
        const float* xp = input + ((size_t)cq * TT + 0) * II + 2 * lane;
        r2[0][256 + lane] = pkrtz(xp[0], xp[1]);
    }

    // ---- persistent per-lane finalize state (tid < 128) ----
    float h_st = 0.f, n_reg = 0.f, n_nxt = 0.f;
    const float* noisep = nullptr;
    float* trajp = nullptr;
    uint32* exw = nullptr;
    int gcf = 0;
    if (tid < 128) {
        gcf    = sl * 128 + tid;
        noisep = noise + (size_t)cq * TT * HH;
        trajp  = traj + (size_t)cq * (TT + 1) * HH;
        h_st   = h0[gcf];
        n_reg  = noisep[gcf];                    // noise(0)
        n_nxt  = noisep[(size_t)HH + gcf];       // noise(1)
        trajp[gcf] = h_st;                       // trajectories[:,0,:]
        exw = ex + (size_t)cq * EXCQ + gcf;      // parity-0 base
    }
    __syncthreads();

    // ---- collect the clique's XCD ids; uniform -> L2-local fast path ----
    if (wv == 0) {
        uint32 v = (1u << 16);
        for (;;) {
            if (lane < SLC)
                v = __hip_atomic_load(aux + cq * SLC + lane,
                                      __ATOMIC_RELAXED, __HIP_MEMORY_SCOPE_AGENT);
            if (__ballot((v >> 16) == 1u) == ~0ull) break;
            __builtin_amdgcn_s_sleep(1);
        }
        uint32 myx = v & 0xFFFFu;
        uint32 x0  = __shfl(myx, 0);
        bool eq = (lane < SLC) ? (myx == x0) : true;
        if (lane == 0) mode_sh = (__ballot(eq) == ~0ull) ? 1 : 0;
    }
    __syncthreads();
    const bool local_mode = (mode_sh != 0);

    uint32* exg0 = ex + (size_t)cq * EXCQ + 4 * (tid & 127);   // used when tid<128

    for (int t = 0; t < TT; ++t) {
        const int p = t & 1;

        // ---- matvec: thread (ks,c) covers 160 k-values of column gc ----
        float acc = 0.f;
        #pragma unroll
        for (int ch = 0; ch < 20; ++ch) {
            int s = ks * 80 + ch * 4;
            half2_t ra = r2[p][s],     rb = r2[p][s + 1];
            half2_t rc = r2[p][s + 2], rd = r2[p][s + 3];
            acc = fdot2f(ra, wr[4 * ch],     acc);
            acc = fdot2f(rb, wr[4 * ch + 1], acc);
            acc = fdot2f(rc, wr[4 * ch + 2], acc);
            acc = fdot2f(rd, wr[4 * ch + 3], acc);
        }
        part[ks][c] = acc;
        __syncthreads();   // B1

        const uint32 tag  = (uint32)(t + 2);   // tag of h(t+1); memset-0 never matches
        const int    poff = p * HH;            // parity offset (words)

        if (tid < 128) {
            // ---- finalize + publish (minimal vmem before the poll) ----
            float mv = part[0][tid] + part[1][tid] + part[2][tid] + part[3][tid];
            float hn = (1.f - ALPHA) * h_st + ALPHA * mv + NOISE_STD * n_reg;
            h_st = hn;
            uint32 r16 = __builtin_bit_cast(uint32,
                           __builtin_amdgcn_cvt_pkrtz(fmaxf(hn, 0.f), 0.f)) & 0xFFFFu;
            uint32 word = (tag << 16) | r16;
            if (local_mode) {
                store1_plain(exw + poff, word);
            } else {
                __hip_atomic_store(exw + poff, word,
                                   __ATOMIC_RELAXED, __HIP_MEMORY_SCOPE_AGENT);
            }

            // ---- gather 4 columns -> r2[p^1] (fan-in 4 producers) ----
            const uint32* g0 = exg0 + poff;
            uint4_t w;
            int spins = 0;
            if (local_mode) {
                for (;;) {
                    w = load4_sc0(g0);
                    if ((w[0] >> 16) == tag && (w[1] >> 16) == tag &&
                        (w[2] >> 16) == tag && (w[3] >> 16) == tag) break;
                    if (++spins > 16) __builtin_amdgcn_s_sleep(1);
                }
            } else {
                for (;;) {
                    w = load4_sc1(g0);
                    if ((w[0] >> 16) == tag && (w[1] >> 16) == tag &&
                        (w[2] >> 16) == tag && (w[3] >> 16) == tag) break;
                    __builtin_amdgcn_s_sleep(1);
                }
            }
            uint32 q0 = (w[0] & 0xFFFFu) | (w[1] << 16);
            uint32 q1 = (w[2] & 0xFFFFu) | (w[3] << 16);
            r2[p ^ 1][2 * tid]     = __builtin_bit_cast(half2_t, q0);
            r2[p ^ 1][2 * tid + 1] = __builtin_bit_cast(half2_t, q1);

            // ---- deferred vmem (latency drains under B2 / next matvec) ----
            trajp[(size_t)(t + 1) * HH + gcf] = h_st;
            n_reg = n_nxt;
            int tn = (t + 2 < TT) ? (t + 2) : (TT - 1);
            n_nxt = noisep[(size_t)tn * HH + gcf];
        } else if (wv == 4 || wv == 5) {
            // ---- out(t-1) = relu(h(t)).wo_eff[:,o], o = 2*sl + (wv-4) ----
            if (t > 0) {
                int oo = wv - 4, o = sl * 2 + oo;
                int k2 = lane * 4;
                float q = 0.f;
                q = fdot2f(r2[p][k2],     wo2[oo][k2],     q);
                q = fdot2f(r2[p][k2 + 1], wo2[oo][k2 + 1], q);
                q = fdot2f(r2[p][k2 + 2], wo2[oo][k2 + 2], q);
                q = fdot2f(r2[p][k2 + 3], wo2[oo][k2 + 3], q);
                #pragma unroll
                for (int d = 32; d >= 1; d >>= 1) q += __shfl_xor(q, d);
                if (lane == 0) out[((size_t)cq * TT + (t - 1)) * OO + o] = q;
            }
        } else if (wv == 6 && lane < 32) {
            // ---- stage x(t+1) into r2[p^1][256..287] ----
            int tn = (t + 1 < TT) ? (t + 1) : (TT - 1);
            const float* xp = input + ((size_t)cq * TT + tn) * II + 2 * lane;
            r2[p ^ 1][256 + lane] = pkrtz(xp[0], xp[1]);
        }
        __syncthreads();   // B2 (r2[p^1] complete; part[] consumed)
    }

    // ---- epilogue: out(TT-1) from r2[0] = relu(h(TT)) ----
    if (wv == 4 || wv == 5) {
        int oo = wv - 4, o = sl * 2 + oo;
        int k2 = lane * 4;
        float q = 0.f;
        q = fdot2f(r2[0][k2],     wo2[oo][k2],     q);
        q = fdot2f(r2[0][k2 + 1], wo2[oo][k2 + 1], q);
        q = fdot2f(r2[0][k2 + 2], wo2[oo][k2 + 2], q);
        q = fdot2f(r2[0][k2 + 3], wo2[oo][k2 + 3], q);
        #pragma unroll
        for (int d = 32; d >= 1; d >>= 1) q += __shfl_xor(q, d);
        if (lane == 0) out[((size_t)cq * TT + (TT - 1)) * OO + o] = q;
    }
}

// ---------------- host launcher ----------------
extern "C" void kernel_launch(void* const* d_in, const int* in_sizes, int n_in,
                              void* d_out, int out_size, void* d_ws, size_t ws_size,
                              hipStream_t stream) {
    const float* input     = (const float*)d_in[0];
    const float* noise     = (const float*)d_in[1];
    const float* wi        = (const float*)d_in[2];
    const float* si        = (const float*)d_in[3];
    const float* wrec      = (const float*)d_in[4];
    const float* bvec      = (const float*)d_in[5];
    const float* wo        = (const float*)d_in[6];
    const float* so        = (const float*)d_in[7];
    const float* wi_mask   = (const float*)d_in[8];
    const float* wrec_mask = (const float*)d_in[9];
    const float* wo_mask   = (const float*)d_in[10];
    const float* h0        = (const float*)d_in[11];

    float* out  = (float*)d_out;
    float* traj = out + (size_t)BB * TT * OO;
    uint32* ex  = (uint32*)d_ws;

    // clear exchange + handshake tags every call (stale-tag safety; replay-safe)
    (void)hipMemsetAsync(d_ws, 0,
        (size_t)(NCLQ * EXCQ + NCLQ * SLC) * sizeof(uint32), stream);

    rnn_b1<<<dim3(NCLQ * SLC), dim3(512), 0, stream>>>(
        input, noise, wi, si, wrec, bvec, wo, so,
        wi_mask, wrec_mask, wo_mask, h0, ex, out, traj);
}